// Round 9
// baseline (41140.097 us; speedup 1.0000x reference)
//
#include <hip/hip_runtime.h>
#include <hip/hip_fp16.h>
#include <math.h>

#define R_DIM 4096
#define I_DIM 64
#define O_DIM 64
#define T_DIM 8192
#define NBLK  256
#define NTHR  512
#define RPB   16          // reservoir rows per block
#define LROWS 4           // rows kept in LDS (rest in registers/AGPRs)

// raw barrier: waits LDS ops only -- deliberately NO vmcnt drain
#define LBAR() asm volatile("s_waitcnt lgkmcnt(0)\n\ts_barrier" ::: "memory")

// fast tanh: exact at saturation, ~1e-6 rel err in between
__device__ __forceinline__ float ftanh(float x) {
    float e = __expf(2.f * x);
    return 1.f - __fdividef(2.f, e + 1.f);
}

// d_ws layout:
//   [0 .. 32KB)   : pair double buffer  2 x 4096 x u32 {tag16, f16 val}
//   [64KB .. )    : Shist[T][R] f32 (HIST mode only, 128 MB)

__global__ __launch_bounds__(NTHR, 2) void esn_persist(
    const float* __restrict__ X, const float* __restrict__ Wres,
    const float* __restrict__ Win, const float* __restrict__ Wout,
    float* __restrict__ out, unsigned* __restrict__ pairs,
    float* __restrict__ Shist, int use_hist)
{
    __shared__ __align__(16) float wlds[LROWS * R_DIM];   // 64 KB weight tile
    __shared__ __align__(16) float sdata[R_DIM + I_DIM];  // state + x_t
    __shared__ float4 red4[8];

    const int tid  = threadIdx.x;
    const int b    = blockIdx.x;
    const int lane = tid & 63;
    const int w    = tid >> 6;        // wave 0..7
    const int rg   = tid >> 7;        // 0..3 : row group
    const int cg   = tid & 127;       // 0..127: column group
    const int R0   = b * RPB;

    // ---- one-time: stage LDS quarter of W_res slice (rows 0..3, 64 KB) ----
    {
        const float4* wsrc = (const float4*)(Wres + (size_t)R0 * R_DIM);
        float4* wdst = (float4*)wlds;
#pragma unroll
        for (int k = 0; k < (LROWS * R_DIM / 4) / NTHR; ++k)
            wdst[k * NTHR + tid] = wsrc[k * NTHR + tid];
    }
    // ---- one-time: register rows (4..15), pinned via asm (may land in AGPRs) ----
    float4 wreg[3][8];
#pragma unroll
    for (int rr = 0; rr < 3; ++rr) {
        const float* rowp = Wres + (size_t)(R0 + 4 + 3 * rg + rr) * R_DIM + cg * 4;
#pragma unroll
        for (int i = 0; i < 8; ++i)
            wreg[rr][i] = *(const float4*)(rowp + i * 512);
    }
#pragma unroll
    for (int rr = 0; rr < 3; ++rr)
#pragma unroll
        for (int i = 0; i < 8; ++i)
            asm volatile("" : "+v"(wreg[rr][i].x), "+v"(wreg[rr][i].y),
                             "+v"(wreg[rr][i].z), "+v"(wreg[rr][i].w));

    float4 wi[4] = {};
    if (cg < 16) {
        wi[0] = *(const float4*)(Win + (size_t)(R0 + rg) * I_DIM + cg * 4);
        wi[1] = *(const float4*)(Win + (size_t)(R0 + 4 + 3 * rg) * I_DIM + cg * 4);
        wi[2] = *(const float4*)(Win + (size_t)(R0 + 5 + 3 * rg) * I_DIM + cg * 4);
        wi[3] = *(const float4*)(Win + (size_t)(R0 + 6 + 3 * rg) * I_DIM + cg * 4);
    }
    float4 wo4[4] = {};
    if (!use_hist && w == 1) {   // fallback readout wave: o = lane
#pragma unroll
        for (int j = 0; j < 4; ++j)
            wo4[j] = *(const float4*)(Wout + (size_t)lane * (I_DIM + R_DIM) + I_DIM + R0 + j * 4);
    }

    for (int t = 0; t < T_DIM; ++t) {
        // ======== STAGE: wave0 -> 64 words (post-tail catch-up), waves 1-7 -> 576 each ========
        if (tid < I_DIM) sdata[R_DIM + tid] = X[(size_t)t * I_DIM + tid];
        {
            unsigned* rbuf = pairs + ((t + 1) & 1) * R_DIM;  // S_{t-1}, tag t
            const unsigned tagmin = (unsigned)t;
            if (w == 0) {
                const int idx = 4032 + lane;
                unsigned p;
                while (1) {
                    p = __hip_atomic_load(&rbuf[idx], __ATOMIC_RELAXED, __HIP_MEMORY_SCOPE_AGENT);
                    if (__all((p >> 16) >= tagmin)) break;
                }
                sdata[idx] = __half2float(__ushort_as_half((unsigned short)(p & 0xFFFFu)));
            } else {
                const int base = (w - 1) * 576 + lane;
                unsigned pv[9];
                while (1) {
                    bool ok = true;
#pragma unroll
                    for (int k = 0; k < 9; ++k) {
                        pv[k] = __hip_atomic_load(&rbuf[base + k * 64],
                                  __ATOMIC_RELAXED, __HIP_MEMORY_SCOPE_AGENT);
                        ok &= (pv[k] >> 16) >= tagmin;
                    }
                    if (__all(ok)) break;
                }
#pragma unroll
                for (int k = 0; k < 9; ++k)
                    sdata[base + k * 64] =
                        __half2float(__ushort_as_half((unsigned short)(pv[k] & 0xFFFFu)));
            }
        }
        LBAR();   // B1: sdata (state + x) visible to all waves

        // ======== COMPUTE: 1 LDS row + 3 REG rows x 32 cols/thread ========
        float acc0 = 0.f, acc1 = 0.f, acc2 = 0.f, acc3 = 0.f;
#pragma unroll
        for (int i = 0; i < 8; ++i) {
            const int col = cg * 4 + i * 512;
            float4 sv = *(const float4*)&sdata[col];
            float4 l0 = *(const float4*)&wlds[rg * R_DIM + col];
            acc0 += l0.x * sv.x + l0.y * sv.y + l0.z * sv.z + l0.w * sv.w;
            acc1 += wreg[0][i].x * sv.x + wreg[0][i].y * sv.y + wreg[0][i].z * sv.z + wreg[0][i].w * sv.w;
            acc2 += wreg[1][i].x * sv.x + wreg[1][i].y * sv.y + wreg[1][i].z * sv.z + wreg[1][i].w * sv.w;
            acc3 += wreg[2][i].x * sv.x + wreg[2][i].y * sv.y + wreg[2][i].z * sv.z + wreg[2][i].w * sv.w;
        }
        if (cg < 16) {
            float4 xv = *(const float4*)&sdata[R_DIM + cg * 4];
            acc0 += wi[0].x * xv.x + wi[0].y * xv.y + wi[0].z * xv.z + wi[0].w * xv.w;
            acc1 += wi[1].x * xv.x + wi[1].y * xv.y + wi[1].z * xv.z + wi[1].w * xv.w;
            acc2 += wi[2].x * xv.x + wi[2].y * xv.y + wi[2].z * xv.z + wi[2].w * xv.w;
            acc3 += wi[3].x * xv.x + wi[3].y * xv.y + wi[3].z * xv.z + wi[3].w * xv.w;
        }
#pragma unroll
        for (int d = 1; d < 64; d <<= 1) {
            acc0 += __shfl_xor(acc0, d);
            acc1 += __shfl_xor(acc1, d);
            acc2 += __shfl_xor(acc2, d);
            acc3 += __shfl_xor(acc3, d);
        }
        if (lane == 0) red4[w] = make_float4(acc0, acc1, acc2, acc3);
        LBAR();   // B2: red4 visible (also fences sdata reads vs t+1 staging writes)

        // ======== TAIL: distributed -- each EVEN wave publishes its 4 rows ========
        if ((w & 1) == 0) {
            if (lane < 4) {
                const int rgp = w >> 1, rr = lane;
                const int row = (rr == 0) ? rgp : (4 + 3 * rgp + (rr - 1));
                float pre = ((const float*)&red4[w])[rr] + ((const float*)&red4[w + 1])[rr];
                float s = ftanh(pre);
                unsigned pack = ((unsigned)(t + 1) << 16)
                              | (unsigned)__half_as_ushort(__float2half(s));
                // distance-2 same-address reuse => no vmcnt fence needed before this store
                __hip_atomic_store(&pairs[(t & 1) * R_DIM + R0 + row], pack,
                                   __ATOMIC_RELAXED, __HIP_MEMORY_SCOPE_AGENT);
                if (use_hist) Shist[(size_t)t * R_DIM + R0 + row] = s;
            }
        } else if (w == 1 && !use_hist) {
            // fallback in-loop readout (fire-and-forget atomics)
            float s = 0.f;
            if (lane < RPB) {
                const int rgp = lane >> 2, rr = lane & 3;
                float pre = ((const float*)&red4[rgp * 2])[rr] + ((const float*)&red4[rgp * 2 + 1])[rr];
                s = ftanh(pre);
            }
            float y = 0.f;
#pragma unroll
            for (int j = 0; j < 16; ++j) {
                const int src = (j < 4) ? (4 * j)
                                        : (4 * ((j - 4) / 3) + ((j - 4) % 3) + 1);
                float sj = __shfl(s, src);
                y += ((const float*)wo4)[j] * sj;
            }
            __hip_atomic_fetch_add(&out[(size_t)t * O_DIM + lane], y,
                                   __ATOMIC_RELAXED, __HIP_MEMORY_SCOPE_AGENT);
        }
        // fallback mode: wave1 reads red4 ungated downstream -> fence re-writers
        if (!use_hist) LBAR();
        // hist mode: t+1 staging gated by B2-ordered publish chain -> no barrier
    }
}

// y_x[t,o] = Wout[o, :64] . x_t  -- plain writes, runs first
__global__ void esn_xpart(const float* __restrict__ X, const float* __restrict__ Wout,
                          float* __restrict__ out)
{
    const int idx = blockIdx.x * blockDim.x + threadIdx.x;  // t*64 + o
    const int t = idx >> 6, o = idx & 63;
    const float4* xr = (const float4*)(X + (size_t)t * I_DIM);
    const float4* wr = (const float4*)(Wout + (size_t)o * (I_DIM + R_DIM));
    float y = 0.f;
#pragma unroll
    for (int j = 0; j < 16; ++j) {
        float4 a = xr[j], b = wr[j];
        y += a.x * b.x + a.y * b.y + a.z * b.z + a.w * b.w;
    }
    out[idx] = y;
}

// HIST mode: out[t,o] += Wout[o, 64:] . Shist[t]  -- massively parallel, no atomics
__global__ void esn_readout(const float* __restrict__ Shist, const float* __restrict__ Wout,
                            float* __restrict__ out)
{
    const int idx = blockIdx.x * blockDim.x + threadIdx.x;  // t*64 + o
    const int t = idx >> 6, o = idx & 63;
    const float4* s4 = (const float4*)(Shist + (size_t)t * R_DIM);
    const float4* w4 = (const float4*)(Wout + (size_t)o * (I_DIM + R_DIM) + I_DIM);
    float y = 0.f;
#pragma unroll 4
    for (int j = 0; j < R_DIM / 4; ++j) {
        float4 a = s4[j], b = w4[j];
        y += a.x * b.x + a.y * b.y + a.z * b.z + a.w * b.w;
    }
    out[idx] += y;
}

extern "C" void kernel_launch(void* const* d_in, const int* in_sizes, int n_in,
                              void* d_out, int out_size, void* d_ws, size_t ws_size,
                              hipStream_t stream)
{
    (void)in_sizes; (void)n_in; (void)out_size;
    const float* X    = (const float*)d_in[0];
    const float* Win  = (const float*)d_in[1];
    const float* Wres = (const float*)d_in[2];
    const float* Wout = (const float*)d_in[3];
    float* out = (float*)d_out;

    unsigned* pairs = (unsigned*)d_ws;
    float* Shist = (float*)((char*)d_ws + 65536);
    const size_t hist_bytes = (size_t)T_DIM * R_DIM * sizeof(float);
    const int use_hist = (ws_size >= 65536 + hist_bytes) ? 1 : 0;

    // reset pair tags every call (stale tags would break polling)
    hipMemsetAsync(d_ws, 0, 2 * R_DIM * sizeof(unsigned), stream);

    // x-part of readout initializes all of d_out
    esn_xpart<<<(T_DIM * O_DIM) / 256, 256, 0, stream>>>(X, Wout, out);

    void* args[] = { (void*)&X, (void*)&Wres, (void*)&Win, (void*)&Wout,
                     (void*)&out, (void*)&pairs, (void*)&Shist, (void*)&use_hist };
    hipLaunchCooperativeKernel((const void*)esn_persist, dim3(NBLK), dim3(NTHR),
                               args, 0, stream);

    if (use_hist)
        esn_readout<<<(T_DIM * O_DIM) / 256, 256, 0, stream>>>(Shist, Wout, out);
}

// Round 10
// 38841.766 us; speedup vs baseline: 1.0592x; 1.0592x over previous
//
#include <hip/hip_runtime.h>
#include <hip/hip_fp16.h>
#include <math.h>

#define R_DIM 4096
#define I_DIM 64
#define O_DIM 64
#define T_DIM 8192
#define NBLK  256
#define NTHR  512
#define RPB   16          // reservoir rows per block
#define LROWS 4           // rows kept in LDS (rest in registers/AGPRs)

// raw barrier: waits LDS ops only -- deliberately NO vmcnt drain
#define LBAR() asm volatile("s_waitcnt lgkmcnt(0)\n\ts_barrier" ::: "memory")

// fast tanh: exact at saturation, ~1e-6 rel err in between
__device__ __forceinline__ float ftanh(float x) {
    float e = __expf(2.f * x);
    return 1.f - __fdividef(2.f, e + 1.f);
}

// d_ws layout:
//   [0 .. 32KB)   : pair double buffer  2 x 4096 x u32 {tag16, f16 val}
//   [64KB .. )    : Shist[T][R] f32 (HIST mode only, 128 MB)

__global__ __launch_bounds__(NTHR, 2) void esn_persist(
    const float* __restrict__ X, const float* __restrict__ Wres,
    const float* __restrict__ Win, const float* __restrict__ Wout,
    float* __restrict__ out, unsigned* __restrict__ pairs,
    float* __restrict__ Shist, int use_hist)
{
    __shared__ __align__(16) float wlds[LROWS * R_DIM];   // 64 KB weight tile
    __shared__ __align__(16) float sdata[R_DIM + I_DIM];  // state + x_t
    __shared__ float4 red4[8];

    const int tid  = threadIdx.x;
    const int b    = blockIdx.x;
    const int lane = tid & 63;
    const int w    = tid >> 6;        // wave 0..7
    const int rg   = tid >> 7;        // 0..3 : row group
    const int cg   = tid & 127;       // 0..127: column group
    const int R0   = b * RPB;

    // ---- one-time: stage LDS quarter of W_res slice (rows 0..3, 64 KB) ----
    {
        const float4* wsrc = (const float4*)(Wres + (size_t)R0 * R_DIM);
        float4* wdst = (float4*)wlds;
#pragma unroll
        for (int k = 0; k < (LROWS * R_DIM / 4) / NTHR; ++k)
            wdst[k * NTHR + tid] = wsrc[k * NTHR + tid];
    }
    // ---- one-time: register rows (4..15), pinned via asm (may land in AGPRs) ----
    float4 wreg[3][8];
#pragma unroll
    for (int rr = 0; rr < 3; ++rr) {
        const float* rowp = Wres + (size_t)(R0 + 4 + 3 * rg + rr) * R_DIM + cg * 4;
#pragma unroll
        for (int i = 0; i < 8; ++i)
            wreg[rr][i] = *(const float4*)(rowp + i * 512);
    }
#pragma unroll
    for (int rr = 0; rr < 3; ++rr)
#pragma unroll
        for (int i = 0; i < 8; ++i)
            asm volatile("" : "+v"(wreg[rr][i].x), "+v"(wreg[rr][i].y),
                             "+v"(wreg[rr][i].z), "+v"(wreg[rr][i].w));

    float4 wi[4] = {};
    if (cg < 16) {
        wi[0] = *(const float4*)(Win + (size_t)(R0 + rg) * I_DIM + cg * 4);
        wi[1] = *(const float4*)(Win + (size_t)(R0 + 4 + 3 * rg) * I_DIM + cg * 4);
        wi[2] = *(const float4*)(Win + (size_t)(R0 + 5 + 3 * rg) * I_DIM + cg * 4);
        wi[3] = *(const float4*)(Win + (size_t)(R0 + 6 + 3 * rg) * I_DIM + cg * 4);
    }
    float4 wo4[4] = {};
    if (!use_hist && w == 1) {   // fallback readout wave: o = lane
#pragma unroll
        for (int j = 0; j < 4; ++j)
            wo4[j] = *(const float4*)(Wout + (size_t)lane * (I_DIM + R_DIM) + I_DIM + R0 + j * 4);
    }

    for (int t = 0; t < T_DIM; ++t) {
        // ======== STAGE: wave0 -> 64 words (after its tail), waves 1-7 -> 576 masked ========
        if (tid < I_DIM) sdata[R_DIM + tid] = X[(size_t)t * I_DIM + tid];
        {
            unsigned* rbuf = pairs + ((t + 1) & 1) * R_DIM;  // S_{t-1}, tag t
            const unsigned tagmin = (unsigned)t;
            if (w == 0) {
                const int idx = 7 * 576 + lane;   // words 4032..4095
                unsigned p;
                do {
                    p = __hip_atomic_load(&rbuf[idx], __ATOMIC_RELAXED, __HIP_MEMORY_SCOPE_AGENT);
                } while (!__all((p >> 16) >= tagmin));
                sdata[idx] = __half2float(__ushort_as_half((unsigned short)(p & 0xFFFFu)));
            } else {
                const int base = (w - 1) * 576 + lane;
                float vals[9];
                unsigned got = 0;
                while (got != 0x1FFu) {
#pragma unroll
                    for (int k = 0; k < 9; ++k) {
                        if (!(got & (1u << k))) {
                            unsigned p = __hip_atomic_load(&rbuf[base + k * 64],
                                          __ATOMIC_RELAXED, __HIP_MEMORY_SCOPE_AGENT);
                            if ((p >> 16) >= tagmin) {
                                vals[k] = __half2float(__ushort_as_half((unsigned short)(p & 0xFFFFu)));
                                got |= 1u << k;
                            }
                        }
                    }
                }
#pragma unroll
                for (int k = 0; k < 9; ++k) sdata[base + k * 64] = vals[k];
            }
        }
        LBAR();   // B1: sdata (state + x) visible to all waves

        // ======== COMPUTE: 1 LDS row + 3 REG rows x 32 cols/thread ========
        float acc0 = 0.f, acc1 = 0.f, acc2 = 0.f, acc3 = 0.f;
#pragma unroll
        for (int i = 0; i < 8; ++i) {
            const int col = cg * 4 + i * 512;
            float4 sv = *(const float4*)&sdata[col];
            float4 l0 = *(const float4*)&wlds[rg * R_DIM + col];
            acc0 += l0.x * sv.x + l0.y * sv.y + l0.z * sv.z + l0.w * sv.w;
            acc1 += wreg[0][i].x * sv.x + wreg[0][i].y * sv.y + wreg[0][i].z * sv.z + wreg[0][i].w * sv.w;
            acc2 += wreg[1][i].x * sv.x + wreg[1][i].y * sv.y + wreg[1][i].z * sv.z + wreg[1][i].w * sv.w;
            acc3 += wreg[2][i].x * sv.x + wreg[2][i].y * sv.y + wreg[2][i].z * sv.z + wreg[2][i].w * sv.w;
        }
        if (cg < 16) {
            float4 xv = *(const float4*)&sdata[R_DIM + cg * 4];
            acc0 += wi[0].x * xv.x + wi[0].y * xv.y + wi[0].z * xv.z + wi[0].w * xv.w;
            acc1 += wi[1].x * xv.x + wi[1].y * xv.y + wi[1].z * xv.z + wi[1].w * xv.w;
            acc2 += wi[2].x * xv.x + wi[2].y * xv.y + wi[2].z * xv.z + wi[2].w * xv.w;
            acc3 += wi[3].x * xv.x + wi[3].y * xv.y + wi[3].z * xv.z + wi[3].w * xv.w;
        }
#pragma unroll
        for (int d = 1; d < 64; d <<= 1) {
            acc0 += __shfl_xor(acc0, d);
            acc1 += __shfl_xor(acc1, d);
            acc2 += __shfl_xor(acc2, d);
            acc3 += __shfl_xor(acc3, d);
        }
        if (lane == 0) red4[w] = make_float4(acc0, acc1, acc2, acc3);
        LBAR();   // B2: red4 visible (also fences sdata reads vs t+1 staging writes)

        // ======== TAIL: wave0 finishes rows, publishes 16 tagged fp16 pairs (1 line) ========
        if (w == 0) {
            // same-address ordering safety for prior-epoch stores (provably ~free)
            asm volatile("s_waitcnt vmcnt(0)" ::: "memory");
            if (lane < RPB) {
                const int rgp = lane >> 2, rr = lane & 3;
                const int row = (rr == 0) ? rgp : (4 + 3 * rgp + (rr - 1));
                float pre = ((const float*)&red4[rgp * 2])[rr] + ((const float*)&red4[rgp * 2 + 1])[rr];
                float s = ftanh(pre);
                unsigned pack = ((unsigned)(t + 1) << 16)
                              | (unsigned)__half_as_ushort(__float2half(s));
                __hip_atomic_store(&pairs[(t & 1) * R_DIM + R0 + row], pack,
                                   __ATOMIC_RELAXED, __HIP_MEMORY_SCOPE_AGENT);
                if (use_hist) Shist[(size_t)t * R_DIM + R0 + row] = s;
            }
        } else if (w == 1 && !use_hist) {
            // fallback in-loop readout (fire-and-forget atomics)
            float s = 0.f;
            if (lane < RPB) {
                const int rgp = lane >> 2, rr = lane & 3;
                float pre = ((const float*)&red4[rgp * 2])[rr] + ((const float*)&red4[rgp * 2 + 1])[rr];
                s = ftanh(pre);
            }
            float y = 0.f;
#pragma unroll
            for (int j = 0; j < 16; ++j) {
                const int src = (j < 4) ? (4 * j)
                                        : (4 * ((j - 4) / 3) + ((j - 4) % 3) + 1);
                float sj = __shfl(s, src);
                y += ((const float*)wo4)[j] * sj;
            }
            __hip_atomic_fetch_add(&out[(size_t)t * O_DIM + lane], y,
                                   __ATOMIC_RELAXED, __HIP_MEMORY_SCOPE_AGENT);
        }
        // fallback mode: wave1 reads red4 ungated downstream -> fence re-writers
        if (!use_hist) LBAR();
        // hist mode: t+1 staging gated by B2-ordered publish chain -> no barrier
    }
}

// y_x[t,o] = Wout[o, :64] . x_t  -- plain writes, runs first
__global__ void esn_xpart(const float* __restrict__ X, const float* __restrict__ Wout,
                          float* __restrict__ out)
{
    const int idx = blockIdx.x * blockDim.x + threadIdx.x;  // t*64 + o
    const int t = idx >> 6, o = idx & 63;
    const float4* xr = (const float4*)(X + (size_t)t * I_DIM);
    const float4* wr = (const float4*)(Wout + (size_t)o * (I_DIM + R_DIM));
    float y = 0.f;
#pragma unroll
    for (int j = 0; j < 16; ++j) {
        float4 a = xr[j], b = wr[j];
        y += a.x * b.x + a.y * b.y + a.z * b.z + a.w * b.w;
    }
    out[idx] = y;
}

// HIST mode: out[t,o] += Wout[o, 64:] . Shist[t]  -- massively parallel, no atomics
__global__ void esn_readout(const float* __restrict__ Shist, const float* __restrict__ Wout,
                            float* __restrict__ out)
{
    const int idx = blockIdx.x * blockDim.x + threadIdx.x;  // t*64 + o
    const int t = idx >> 6, o = idx & 63;
    const float4* s4 = (const float4*)(Shist + (size_t)t * R_DIM);
    const float4* w4 = (const float4*)(Wout + (size_t)o * (I_DIM + R_DIM) + I_DIM);
    float y = 0.f;
#pragma unroll 4
    for (int j = 0; j < R_DIM / 4; ++j) {
        float4 a = s4[j], b = w4[j];
        y += a.x * b.x + a.y * b.y + a.z * b.z + a.w * b.w;
    }
    out[idx] += y;
}

extern "C" void kernel_launch(void* const* d_in, const int* in_sizes, int n_in,
                              void* d_out, int out_size, void* d_ws, size_t ws_size,
                              hipStream_t stream)
{
    (void)in_sizes; (void)n_in; (void)out_size;
    const float* X    = (const float*)d_in[0];
    const float* Win  = (const float*)d_in[1];
    const float* Wres = (const float*)d_in[2];
    const float* Wout = (const float*)d_in[3];
    float* out = (float*)d_out;

    unsigned* pairs = (unsigned*)d_ws;
    float* Shist = (float*)((char*)d_ws + 65536);
    const size_t hist_bytes = (size_t)T_DIM * R_DIM * sizeof(float);
    const int use_hist = (ws_size >= 65536 + hist_bytes) ? 1 : 0;

    // reset pair tags every call (stale tags would break polling)
    hipMemsetAsync(d_ws, 0, 2 * R_DIM * sizeof(unsigned), stream);

    // x-part of readout initializes all of d_out
    esn_xpart<<<(T_DIM * O_DIM) / 256, 256, 0, stream>>>(X, Wout, out);

    void* args[] = { (void*)&X, (void*)&Wres, (void*)&Win, (void*)&Wout,
                     (void*)&out, (void*)&pairs, (void*)&Shist, (void*)&use_hist };
    hipLaunchCooperativeKernel((const void*)esn_persist, dim3(NBLK), dim3(NTHR),
                               args, 0, stream);

    if (use_hist)
        esn_readout<<<(T_DIM * O_DIM) / 256, 256, 0, stream>>>(Shist, Wout, out);
}

// Round 11
// 32574.429 us; speedup vs baseline: 1.2630x; 1.1924x over previous
//
#include <hip/hip_runtime.h>
#include <hip/hip_fp16.h>
#include <math.h>

#define R_DIM 4096
#define I_DIM 64
#define O_DIM 64
#define T_DIM 8192
#define NBLK  256
#define NTHR  512
#define RPB   16          // reservoir rows per block

// raw barrier: waits LDS ops only -- deliberately NO vmcnt drain
#define LBAR() asm volatile("s_waitcnt lgkmcnt(0)\n\ts_barrier" ::: "memory")

// fast tanh: exact at saturation, ~1e-6 rel err in between
__device__ __forceinline__ float ftanh(float x) {
    float e = __expf(2.f * x);
    return 1.f - __fdividef(2.f, e + 1.f);
}

// d_ws layout:
//   [0 .. 32KB)   : pair double buffer  2 x 4096 x u32 {tag16, f16 val}
//   [64KB .. )    : Shist[T][R] f32 (HIST mode only, 128 MB)

__global__ __launch_bounds__(NTHR, 2) void esn_persist(
    const float* __restrict__ X, const float* __restrict__ Wres,
    const float* __restrict__ Win, const float* __restrict__ Wout,
    float* __restrict__ out, unsigned* __restrict__ pairs,
    float* __restrict__ Shist, int use_hist)
{
    __shared__ float wred[2][8][RPB];   // per-wave row partials, parity dbuf
    __shared__ float wred_x[RPB];       // Win @ x_t per row (wave0-owned)
    __shared__ float snew[RPB];         // published state (fallback readout)

    const int tid  = threadIdx.x;
    const int b    = blockIdx.x;
    const int lane = tid & 63;
    const int w    = tid >> 6;        // wave 0..7
    const int R0   = b * RPB;

    // ---- one-time: K-split weights -- wave w, lane l owns cols w*512 + k*64 + l,
    //      all 16 rows: 128 floats in registers, pinned via asm ----
    float wr[RPB][8];
#pragma unroll
    for (int r = 0; r < RPB; ++r) {
        const float* rowp = Wres + (size_t)(R0 + r) * R_DIM + w * 512 + lane;
#pragma unroll
        for (int k = 0; k < 8; ++k)
            wr[r][k] = rowp[k * 64];
    }
#pragma unroll
    for (int r = 0; r < RPB; ++r)
        asm volatile("" : "+v"(wr[r][0]), "+v"(wr[r][1]), "+v"(wr[r][2]), "+v"(wr[r][3]),
                          "+v"(wr[r][4]), "+v"(wr[r][5]), "+v"(wr[r][6]), "+v"(wr[r][7]));

    // wave0: Win slice -- lane l covers row l>>2, cols (l&3)*16 .. +16
    float winv[16];
#pragma unroll
    for (int j = 0; j < 16; ++j) winv[j] = 0.f;
    if (w == 0) {
        const float* wp = Win + (size_t)(R0 + (lane >> 2)) * I_DIM + (lane & 3) * 16;
#pragma unroll
        for (int j = 0; j < 16; ++j) winv[j] = wp[j];
    }
    float4 wo4[4] = {};
    if (!use_hist && w == 1) {   // fallback readout wave: o = lane
#pragma unroll
        for (int j = 0; j < 4; ++j)
            wo4[j] = *(const float4*)(Wout + (size_t)lane * (I_DIM + R_DIM) + I_DIM + R0 + j * 4);
    }

    for (int t = 0; t < T_DIM; ++t) {
        // ======== wave0: Win @ x_t (independent of other blocks, hides under polls) ========
        if (w == 0) {
            const float* xp = X + (size_t)t * I_DIM + (lane & 3) * 16;
            float acc = 0.f;
#pragma unroll
            for (int j = 0; j < 16; ++j) acc += winv[j] * xp[j];
            acc += __shfl_xor(acc, 1);
            acc += __shfl_xor(acc, 2);
            if ((lane & 3) == 0) wred_x[lane >> 2] = acc;
        }

        // ======== poll own 512-word chunk (masked, R8-style) ========
        float vals[8];
        {
            unsigned* rbuf = pairs + ((t + 1) & 1) * R_DIM;  // S_{t-1}, tag t
            const unsigned tagmin = (unsigned)t;
            const int base = w * 512 + lane;
            unsigned got = 0;
            while (got != 0xFFu) {
#pragma unroll
                for (int k = 0; k < 8; ++k) {
                    if (!(got & (1u << k))) {
                        unsigned p = __hip_atomic_load(&rbuf[base + k * 64],
                                      __ATOMIC_RELAXED, __HIP_MEMORY_SCOPE_AGENT);
                        if ((p >> 16) >= tagmin) {
                            vals[k] = __half2float(__ushort_as_half((unsigned short)(p & 0xFFFFu)));
                            got |= 1u << k;
                        }
                    }
                }
            }
        }

        // ======== compute: 16 rows x 8 owned cols, all in registers ========
        float acc[RPB];
#pragma unroll
        for (int r = 0; r < RPB; ++r) acc[r] = 0.f;
#pragma unroll
        for (int k = 0; k < 8; ++k) {
            const float s = vals[k];
#pragma unroll
            for (int r = 0; r < RPB; ++r) acc[r] += wr[r][k] * s;
        }

        // ======== specialized butterfly: 16 accs over 64 lanes (~64 ops) ========
        // offsets 1,2,4,8 halve acc count assigning row bits 3,2,1,0; then 16,32 sum groups
#pragma unroll
        for (int j = 0; j < 8; ++j) {
            const bool bb = lane & 1;
            float send = bb ? acc[j] : acc[j + 8];
            float keep = bb ? acc[j + 8] : acc[j];
            acc[j] = keep + __shfl_xor(send, 1);
        }
#pragma unroll
        for (int j = 0; j < 4; ++j) {
            const bool bb = lane & 2;
            float send = bb ? acc[j] : acc[j + 4];
            float keep = bb ? acc[j + 4] : acc[j];
            acc[j] = keep + __shfl_xor(send, 2);
        }
#pragma unroll
        for (int j = 0; j < 2; ++j) {
            const bool bb = lane & 4;
            float send = bb ? acc[j] : acc[j + 2];
            float keep = bb ? acc[j + 2] : acc[j];
            acc[j] = keep + __shfl_xor(send, 4);
        }
        {
            const bool bb = lane & 8;
            float send = bb ? acc[0] : acc[1];
            float keep = bb ? acc[1] : acc[0];
            acc[0] = keep + __shfl_xor(send, 8);
        }
        acc[0] += __shfl_xor(acc[0], 16);
        acc[0] += __shfl_xor(acc[0], 32);
        // lane l (<16) holds row rev4(l)
        const int rl = ((lane & 1) << 3) | ((lane & 2) << 1) | ((lane & 4) >> 1) | ((lane & 8) >> 3);
        if (lane < 16) wred[t & 1][w][rl] = acc[0];

        LBAR();   // the ONLY per-step barrier: all wave partials + wred_x visible

        // ======== TAIL: wave0 sums partials, tanh, publishes 1 coalesced line ========
        if (w == 0) {
            // same-address ordering for t-2 publishes / t-1 Shist (empirically ~free)
            asm volatile("s_waitcnt vmcnt(0)" ::: "memory");
            if (lane < RPB) {
                float pre = wred_x[lane];
#pragma unroll
                for (int wv = 0; wv < 8; ++wv) pre += wred[t & 1][wv][lane];
                float s = ftanh(pre);
                unsigned pack = ((unsigned)(t + 1) << 16)
                              | (unsigned)__half_as_ushort(__float2half(s));
                __hip_atomic_store(&pairs[(t & 1) * R_DIM + R0 + lane], pack,
                                   __ATOMIC_RELAXED, __HIP_MEMORY_SCOPE_AGENT);
                if (use_hist) Shist[(size_t)t * R_DIM + R0 + lane] = s;
                snew[lane] = s;
            }
        }

        if (!use_hist) {
            LBAR();   // snew visible to wave1
            if (w == 1) {
                float y = 0.f;
#pragma unroll
                for (int j = 0; j < 16; ++j)
                    y += ((const float*)wo4)[j] * snew[j];
                __hip_atomic_fetch_add(&out[(size_t)t * O_DIM + lane], y,
                                       __ATOMIC_RELAXED, __HIP_MEMORY_SCOPE_AGENT);
            }
            // next-step wred writes go to opposite parity; snew rewritten only after
            // the NEXT step's LBAR, which wave1 reaches after these reads -> safe
        }
    }
}

// y_x[t,o] = Wout[o, :64] . x_t  -- plain writes, runs first
__global__ void esn_xpart(const float* __restrict__ X, const float* __restrict__ Wout,
                          float* __restrict__ out)
{
    const int idx = blockIdx.x * blockDim.x + threadIdx.x;  // t*64 + o
    const int t = idx >> 6, o = idx & 63;
    const float4* xr = (const float4*)(X + (size_t)t * I_DIM);
    const float4* wr = (const float4*)(Wout + (size_t)o * (I_DIM + R_DIM));
    float y = 0.f;
#pragma unroll
    for (int j = 0; j < 16; ++j) {
        float4 a = xr[j], b = wr[j];
        y += a.x * b.x + a.y * b.y + a.z * b.z + a.w * b.w;
    }
    out[idx] = y;
}

// HIST mode: out[t,o] += Wout[o, 64:] . Shist[t]  -- massively parallel, no atomics
__global__ void esn_readout(const float* __restrict__ Shist, const float* __restrict__ Wout,
                            float* __restrict__ out)
{
    const int idx = blockIdx.x * blockDim.x + threadIdx.x;  // t*64 + o
    const int t = idx >> 6, o = idx & 63;
    const float4* s4 = (const float4*)(Shist + (size_t)t * R_DIM);
    const float4* w4 = (const float4*)(Wout + (size_t)o * (I_DIM + R_DIM) + I_DIM);
    float y = 0.f;
#pragma unroll 4
    for (int j = 0; j < R_DIM / 4; ++j) {
        float4 a = s4[j], b = w4[j];
        y += a.x * b.x + a.y * b.y + a.z * b.z + a.w * b.w;
    }
    out[idx] += y;
}

extern "C" void kernel_launch(void* const* d_in, const int* in_sizes, int n_in,
                              void* d_out, int out_size, void* d_ws, size_t ws_size,
                              hipStream_t stream)
{
    (void)in_sizes; (void)n_in; (void)out_size;
    const float* X    = (const float*)d_in[0];
    const float* Win  = (const float*)d_in[1];
    const float* Wres = (const float*)d_in[2];
    const float* Wout = (const float*)d_in[3];
    float* out = (float*)d_out;

    unsigned* pairs = (unsigned*)d_ws;
    float* Shist = (float*)((char*)d_ws + 65536);
    const size_t hist_bytes = (size_t)T_DIM * R_DIM * sizeof(float);
    const int use_hist = (ws_size >= 65536 + hist_bytes) ? 1 : 0;

    // reset pair tags every call (stale tags would break polling)
    hipMemsetAsync(d_ws, 0, 2 * R_DIM * sizeof(unsigned), stream);

    // x-part of readout initializes all of d_out
    esn_xpart<<<(T_DIM * O_DIM) / 256, 256, 0, stream>>>(X, Wout, out);

    void* args[] = { (void*)&X, (void*)&Wres, (void*)&Win, (void*)&Wout,
                     (void*)&out, (void*)&pairs, (void*)&Shist, (void*)&use_hist };
    hipLaunchCooperativeKernel((const void*)esn_persist, dim3(NBLK), dim3(NTHR),
                               args, 0, stream);

    if (use_hist)
        esn_readout<<<(T_DIM * O_DIM) / 256, 256, 0, stream>>>(Shist, Wout, out);
}

// Round 12
// 32461.066 us; speedup vs baseline: 1.2674x; 1.0035x over previous
//
#include <hip/hip_runtime.h>
#include <hip/hip_fp16.h>
#include <math.h>

#define R_DIM 4096
#define I_DIM 64
#define O_DIM 64
#define T_DIM 8192
#define NBLK  256
#define NTHR  512
#define RPB   16          // reservoir rows per block

// raw barrier: waits LDS ops only -- deliberately NO vmcnt drain
#define LBAR() asm volatile("s_waitcnt lgkmcnt(0)\n\ts_barrier" ::: "memory")

// fast tanh: exact at saturation, ~1e-6 rel err in between
__device__ __forceinline__ float ftanh(float x) {
    float e = __expf(2.f * x);
    return 1.f - __fdividef(2.f, e + 1.f);
}

// d_ws layout:
//   [0 .. 32KB)   : pair double buffer  2 x 4096 x u32 {tag16, f16 val}
//   [64KB .. )    : Shist[T][R] f32 (HIST mode only, 128 MB)

__global__ __launch_bounds__(NTHR, 2) void esn_persist(
    const float* __restrict__ X, const float* __restrict__ Wres,
    const float* __restrict__ Win, const float* __restrict__ Wout,
    float* __restrict__ out, unsigned* __restrict__ pairs,
    float* __restrict__ Shist, int use_hist)
{
    __shared__ float wred[2][8][RPB];   // per-wave row partials, parity dbuf
    __shared__ float wred_x[RPB];       // Win @ x_t per row (wave0-owned)
    __shared__ float snew[RPB];         // published state (fallback readout)

    const int tid  = threadIdx.x;
    const int b    = blockIdx.x;
    const int lane = tid & 63;
    const int w    = tid >> 6;        // wave 0..7
    const int R0   = b * RPB;

    // ---- one-time: K-split weights -- wave w, lane l owns cols w*512 + k*64 + l,
    //      all 16 rows: 128 floats in registers, pinned via asm ----
    float wr[RPB][8];
#pragma unroll
    for (int r = 0; r < RPB; ++r) {
        const float* rowp = Wres + (size_t)(R0 + r) * R_DIM + w * 512 + lane;
#pragma unroll
        for (int k = 0; k < 8; ++k)
            wr[r][k] = rowp[k * 64];
    }
#pragma unroll
    for (int r = 0; r < RPB; ++r)
        asm volatile("" : "+v"(wr[r][0]), "+v"(wr[r][1]), "+v"(wr[r][2]), "+v"(wr[r][3]),
                          "+v"(wr[r][4]), "+v"(wr[r][5]), "+v"(wr[r][6]), "+v"(wr[r][7]));

    // wave0: Win slice -- lane l covers row l>>2, cols (l&3)*16 .. +16
    float winv[16];
#pragma unroll
    for (int j = 0; j < 16; ++j) winv[j] = 0.f;
    float4 xv4[4] = {};
    if (w == 0) {
        const float* wp = Win + (size_t)(R0 + (lane >> 2)) * I_DIM + (lane & 3) * 16;
#pragma unroll
        for (int j = 0; j < 16; ++j) winv[j] = wp[j];
        // preload x_0 into registers
        const float4* xp = (const float4*)(X + (lane & 3) * 16);
#pragma unroll
        for (int j = 0; j < 4; ++j) xv4[j] = xp[j];
    }
    float4 wo4[4] = {};
    if (!use_hist && w == 1) {   // fallback readout wave: o = lane
#pragma unroll
        for (int j = 0; j < 4; ++j)
            wo4[j] = *(const float4*)(Wout + (size_t)lane * (I_DIM + R_DIM) + I_DIM + R0 + j * 4);
    }

    for (int t = 0; t < T_DIM; ++t) {
        // ======== wave0: Win @ x_t from prefetched regs; then issue x_{t+1} loads ========
        if (w == 0) {
            const float* xs = (const float*)xv4;
            float acc = 0.f;
#pragma unroll
            for (int j = 0; j < 16; ++j) acc += winv[j] * xs[j];
            acc += __shfl_xor(acc, 1);
            acc += __shfl_xor(acc, 2);
            if ((lane & 3) == 0) wred_x[lane >> 2] = acc;
            if (t + 1 < T_DIM) {   // prefetch next x; lands well before next tail
                const float4* xp = (const float4*)(X + (size_t)(t + 1) * I_DIM + (lane & 3) * 16);
#pragma unroll
                for (int j = 0; j < 4; ++j) xv4[j] = xp[j];
            }
        }

        // ======== poll own 512-word chunk; FMA-on-arrival ========
        float acc[RPB];
#pragma unroll
        for (int r = 0; r < RPB; ++r) acc[r] = 0.f;
        {
            unsigned* rbuf = pairs + ((t + 1) & 1) * R_DIM;  // S_{t-1}, tag t
            const unsigned tagmin = (unsigned)t;
            const int base = w * 512 + lane;
            unsigned got = 0;
            __builtin_amdgcn_s_setprio(0);   // spin phase: deprioritize vs compute waves
            while (got != 0xFFu) {
#pragma unroll
                for (int k = 0; k < 8; ++k) {
                    if (!(got & (1u << k))) {
                        unsigned p = __hip_atomic_load(&rbuf[base + k * 64],
                                      __ATOMIC_RELAXED, __HIP_MEMORY_SCOPE_AGENT);
                        if ((p >> 16) >= tagmin) {
                            got |= 1u << k;
                            const float s = __half2float(__ushort_as_half((unsigned short)(p & 0xFFFFu)));
#pragma unroll
                            for (int r = 0; r < RPB; ++r) acc[r] += wr[r][k] * s;
                        }
                    }
                }
            }
            __builtin_amdgcn_s_setprio(1);   // data ready: this wave is on the critical path
        }

        // ======== specialized butterfly: 16 accs over 64 lanes (~64 ops) ========
#pragma unroll
        for (int j = 0; j < 8; ++j) {
            const bool bb = lane & 1;
            float send = bb ? acc[j] : acc[j + 8];
            float keep = bb ? acc[j + 8] : acc[j];
            acc[j] = keep + __shfl_xor(send, 1);
        }
#pragma unroll
        for (int j = 0; j < 4; ++j) {
            const bool bb = lane & 2;
            float send = bb ? acc[j] : acc[j + 4];
            float keep = bb ? acc[j + 4] : acc[j];
            acc[j] = keep + __shfl_xor(send, 2);
        }
#pragma unroll
        for (int j = 0; j < 2; ++j) {
            const bool bb = lane & 4;
            float send = bb ? acc[j] : acc[j + 2];
            float keep = bb ? acc[j + 2] : acc[j];
            acc[j] = keep + __shfl_xor(send, 4);
        }
        {
            const bool bb = lane & 8;
            float send = bb ? acc[0] : acc[1];
            float keep = bb ? acc[1] : acc[0];
            acc[0] = keep + __shfl_xor(send, 8);
        }
        acc[0] += __shfl_xor(acc[0], 16);
        acc[0] += __shfl_xor(acc[0], 32);
        // lane l (<16) holds row rev4(l)
        const int rl = ((lane & 1) << 3) | ((lane & 2) << 1) | ((lane & 4) >> 1) | ((lane & 8) >> 3);
        if (lane < 16) wred[t & 1][w][rl] = acc[0];

        LBAR();   // the ONLY per-step barrier: all wave partials + wred_x visible

        // ======== TAIL: wave0 sums partials, tanh, publishes 1 coalesced line ========
        if (w == 0) {
            // same-address ordering for t-2 publishes / prefetches (empirically ~free)
            asm volatile("s_waitcnt vmcnt(0)" ::: "memory");
            if (lane < RPB) {
                float pre = wred_x[lane];
#pragma unroll
                for (int wv = 0; wv < 8; ++wv) pre += wred[t & 1][wv][lane];
                float s = ftanh(pre);
                unsigned pack = ((unsigned)(t + 1) << 16)
                              | (unsigned)__half_as_ushort(__float2half(s));
                __hip_atomic_store(&pairs[(t & 1) * R_DIM + R0 + lane], pack,
                                   __ATOMIC_RELAXED, __HIP_MEMORY_SCOPE_AGENT);
                if (use_hist) Shist[(size_t)t * R_DIM + R0 + lane] = s;
                snew[lane] = s;
            }
        }

        if (!use_hist) {
            LBAR();   // snew visible to wave1
            if (w == 1) {
                float y = 0.f;
#pragma unroll
                for (int j = 0; j < 16; ++j)
                    y += ((const float*)wo4)[j] * snew[j];
                __hip_atomic_fetch_add(&out[(size_t)t * O_DIM + lane], y,
                                       __ATOMIC_RELAXED, __HIP_MEMORY_SCOPE_AGENT);
            }
        }
    }
}

// y_x[t,o] = Wout[o, :64] . x_t  -- plain writes, runs first
__global__ void esn_xpart(const float* __restrict__ X, const float* __restrict__ Wout,
                          float* __restrict__ out)
{
    const int idx = blockIdx.x * blockDim.x + threadIdx.x;  // t*64 + o
    const int t = idx >> 6, o = idx & 63;
    const float4* xr = (const float4*)(X + (size_t)t * I_DIM);
    const float4* wr = (const float4*)(Wout + (size_t)o * (I_DIM + R_DIM));
    float y = 0.f;
#pragma unroll
    for (int j = 0; j < 16; ++j) {
        float4 a = xr[j], b = wr[j];
        y += a.x * b.x + a.y * b.y + a.z * b.z + a.w * b.w;
    }
    out[idx] = y;
}

// HIST mode: out[t,o] += Wout[o, 64:] . Shist[t]  -- massively parallel, no atomics
__global__ void esn_readout(const float* __restrict__ Shist, const float* __restrict__ Wout,
                            float* __restrict__ out)
{
    const int idx = blockIdx.x * blockDim.x + threadIdx.x;  // t*64 + o
    const int t = idx >> 6, o = idx & 63;
    const float4* s4 = (const float4*)(Shist + (size_t)t * R_DIM);
    const float4* w4 = (const float4*)(Wout + (size_t)o * (I_DIM + R_DIM) + I_DIM);
    float y = 0.f;
#pragma unroll 4
    for (int j = 0; j < R_DIM / 4; ++j) {
        float4 a = s4[j], b = w4[j];
        y += a.x * b.x + a.y * b.y + a.z * b.z + a.w * b.w;
    }
    out[idx] += y;
}

extern "C" void kernel_launch(void* const* d_in, const int* in_sizes, int n_in,
                              void* d_out, int out_size, void* d_ws, size_t ws_size,
                              hipStream_t stream)
{
    (void)in_sizes; (void)n_in; (void)out_size;
    const float* X    = (const float*)d_in[0];
    const float* Win  = (const float*)d_in[1];
    const float* Wres = (const float*)d_in[2];
    const float* Wout = (const float*)d_in[3];
    float* out = (float*)d_out;

    unsigned* pairs = (unsigned*)d_ws;
    float* Shist = (float*)((char*)d_ws + 65536);
    const size_t hist_bytes = (size_t)T_DIM * R_DIM * sizeof(float);
    const int use_hist = (ws_size >= 65536 + hist_bytes) ? 1 : 0;

    // reset pair tags every call (stale tags would break polling)
    hipMemsetAsync(d_ws, 0, 2 * R_DIM * sizeof(unsigned), stream);

    // x-part of readout initializes all of d_out
    esn_xpart<<<(T_DIM * O_DIM) / 256, 256, 0, stream>>>(X, Wout, out);

    void* args[] = { (void*)&X, (void*)&Wres, (void*)&Win, (void*)&Wout,
                     (void*)&out, (void*)&pairs, (void*)&Shist, (void*)&use_hist };
    hipLaunchCooperativeKernel((const void*)esn_persist, dim3(NBLK), dim3(NTHR),
                               args, 0, stream);

    if (use_hist)
        esn_readout<<<(T_DIM * O_DIM) / 256, 256, 0, stream>>>(Shist, Wout, out);
}

// Round 13
// 32026.657 us; speedup vs baseline: 1.2846x; 1.0136x over previous
//
#include <hip/hip_runtime.h>
#include <hip/hip_fp16.h>
#include <math.h>

#define R_DIM 4096
#define I_DIM 64
#define O_DIM 64
#define T_DIM 8192
#define NBLK  256
#define NTHR  512
#define RPB   16          // reservoir rows per block

// raw barrier: waits LDS ops only -- deliberately NO vmcnt drain
#define LBAR() asm volatile("s_waitcnt lgkmcnt(0)\n\ts_barrier" ::: "memory")

// fast tanh: exact at saturation, ~1e-6 rel err in between
__device__ __forceinline__ float ftanh(float x) {
    float e = __expf(2.f * x);
    return 1.f - __fdividef(2.f, e + 1.f);
}

// d_ws layout:
//   [0 .. 32KB)   : pair double buffer  2 x 4096 x u32 {tag16, f16 val}
//   [64KB .. )    : Shist[T][R] f32 (HIST mode only, 128 MB)

__global__ __launch_bounds__(NTHR, 2) void esn_persist(
    const float* __restrict__ X, const float* __restrict__ Wres,
    const float* __restrict__ Win, const float* __restrict__ Wout,
    float* __restrict__ out, unsigned* __restrict__ pairs,
    float* __restrict__ Shist, int use_hist)
{
    __shared__ float wred[2][8][RPB];   // per-wave row partials, parity dbuf
    __shared__ float wred_x[RPB];       // Win @ x_t per row (wave0-owned)
    __shared__ float snew[RPB];         // published state (fallback readout)

    const int tid  = threadIdx.x;
    const int b    = blockIdx.x;
    const int lane = tid & 63;
    const int w    = tid >> 6;        // wave 0..7
    const int R0   = b * RPB;

    // ---- one-time: K-split weights -- wave w, lane l owns cols w*512 + k*64 + l,
    //      all 16 rows: 128 floats in registers, pinned via asm ----
    float wr[RPB][8];
#pragma unroll
    for (int r = 0; r < RPB; ++r) {
        const float* rowp = Wres + (size_t)(R0 + r) * R_DIM + w * 512 + lane;
#pragma unroll
        for (int k = 0; k < 8; ++k)
            wr[r][k] = rowp[k * 64];
    }
#pragma unroll
    for (int r = 0; r < RPB; ++r)
        asm volatile("" : "+v"(wr[r][0]), "+v"(wr[r][1]), "+v"(wr[r][2]), "+v"(wr[r][3]),
                          "+v"(wr[r][4]), "+v"(wr[r][5]), "+v"(wr[r][6]), "+v"(wr[r][7]));

    // wave0: Win slice -- lane l covers row l>>2, cols (l&3)*16 .. +16
    float winv[16];
#pragma unroll
    for (int j = 0; j < 16; ++j) winv[j] = 0.f;
    float4 xv4[4] = {};
    if (w == 0) {
        const float* wp = Win + (size_t)(R0 + (lane >> 2)) * I_DIM + (lane & 3) * 16;
#pragma unroll
        for (int j = 0; j < 16; ++j) winv[j] = wp[j];
        const float4* xp = (const float4*)(X + (lane & 3) * 16);
#pragma unroll
        for (int j = 0; j < 4; ++j) xv4[j] = xp[j];
    }
    float4 wo4[4] = {};
    if (!use_hist && w == 1) {   // fallback readout wave: o = lane
#pragma unroll
        for (int j = 0; j < 4; ++j)
            wo4[j] = *(const float4*)(Wout + (size_t)lane * (I_DIM + R_DIM) + I_DIM + R0 + j * 4);
    }

    for (int t = 0; t < T_DIM; ++t) {
        // ======== wave0: Win @ x_t from prefetched regs; then issue x_{t+1} loads ========
        if (w == 0) {
            const float* xs = (const float*)xv4;
            float acc = 0.f;
#pragma unroll
            for (int j = 0; j < 16; ++j) acc += winv[j] * xs[j];
            acc += __shfl_xor(acc, 1);
            acc += __shfl_xor(acc, 2);
            if ((lane & 3) == 0) wred_x[lane >> 2] = acc;
            if (t + 1 < T_DIM) {
                const float4* xp = (const float4*)(X + (size_t)(t + 1) * I_DIM + (lane & 3) * 16);
#pragma unroll
                for (int j = 0; j < 4; ++j) xv4[j] = xp[j];
            }
        }

        // ======== poll own 512-word chunk: dead-zone probe then hot sweep ========
        float acc[RPB];
#pragma unroll
        for (int r = 0; r < RPB; ++r) acc[r] = 0.f;
        {
            unsigned* rbuf = pairs + ((t + 1) & 1) * R_DIM;  // S_{t-1}, tag t
            const unsigned tagmin = (unsigned)t;
            const int base = w * 512 + lane;
            __builtin_amdgcn_s_setprio(0);   // spin phase: deprioritize
            // ---- dead zone: probe ONLY k=0 (1 line/wave/round, ~50x less IC pressure) ----
            unsigned p0;
            while (1) {
                p0 = __hip_atomic_load(&rbuf[base], __ATOMIC_RELAXED, __HIP_MEMORY_SCOPE_AGENT);
                if ((p0 >> 16) >= tagmin) break;
                __builtin_amdgcn_s_sleep(4);
            }
            {
                const float s = __half2float(__ushort_as_half((unsigned short)(p0 & 0xFFFFu)));
#pragma unroll
                for (int r = 0; r < RPB; ++r) acc[r] += wr[r][0] * s;
            }
            // ---- hot phase: masked full sweeps, FMA-on-arrival, no sleep ----
            unsigned got = 1u;
            while (got != 0xFFu) {
#pragma unroll
                for (int k = 1; k < 8; ++k) {
                    if (!(got & (1u << k))) {
                        unsigned p = __hip_atomic_load(&rbuf[base + k * 64],
                                      __ATOMIC_RELAXED, __HIP_MEMORY_SCOPE_AGENT);
                        if ((p >> 16) >= tagmin) {
                            got |= 1u << k;
                            const float s = __half2float(__ushort_as_half((unsigned short)(p & 0xFFFFu)));
#pragma unroll
                            for (int r = 0; r < RPB; ++r) acc[r] += wr[r][k] * s;
                        }
                    }
                }
            }
            __builtin_amdgcn_s_setprio(1);   // data ready: critical path
        }

        // ======== specialized butterfly: 16 accs over 64 lanes (~64 ops) ========
#pragma unroll
        for (int j = 0; j < 8; ++j) {
            const bool bb = lane & 1;
            float send = bb ? acc[j] : acc[j + 8];
            float keep = bb ? acc[j + 8] : acc[j];
            acc[j] = keep + __shfl_xor(send, 1);
        }
#pragma unroll
        for (int j = 0; j < 4; ++j) {
            const bool bb = lane & 2;
            float send = bb ? acc[j] : acc[j + 4];
            float keep = bb ? acc[j + 4] : acc[j];
            acc[j] = keep + __shfl_xor(send, 2);
        }
#pragma unroll
        for (int j = 0; j < 2; ++j) {
            const bool bb = lane & 4;
            float send = bb ? acc[j] : acc[j + 2];
            float keep = bb ? acc[j + 2] : acc[j];
            acc[j] = keep + __shfl_xor(send, 4);
        }
        {
            const bool bb = lane & 8;
            float send = bb ? acc[0] : acc[1];
            float keep = bb ? acc[1] : acc[0];
            acc[0] = keep + __shfl_xor(send, 8);
        }
        acc[0] += __shfl_xor(acc[0], 16);
        acc[0] += __shfl_xor(acc[0], 32);
        const int rl = ((lane & 1) << 3) | ((lane & 2) << 1) | ((lane & 4) >> 1) | ((lane & 8) >> 3);
        if (lane < 16) wred[t & 1][w][rl] = acc[0];

        LBAR();   // the ONLY per-step barrier: all wave partials + wred_x visible

        // ======== TAIL: wave0 sums partials, tanh, publishes 1 coalesced line ========
        if (w == 0) {
            asm volatile("s_waitcnt vmcnt(0)" ::: "memory");
            if (lane < RPB) {
                float pre = wred_x[lane];
#pragma unroll
                for (int wv = 0; wv < 8; ++wv) pre += wred[t & 1][wv][lane];
                float s = ftanh(pre);
                unsigned pack = ((unsigned)(t + 1) << 16)
                              | (unsigned)__half_as_ushort(__float2half(s));
                __hip_atomic_store(&pairs[(t & 1) * R_DIM + R0 + lane], pack,
                                   __ATOMIC_RELAXED, __HIP_MEMORY_SCOPE_AGENT);
                if (use_hist) Shist[(size_t)t * R_DIM + R0 + lane] = s;
                snew[lane] = s;
            }
        }

        if (!use_hist) {
            LBAR();   // snew visible to wave1
            if (w == 1) {
                float y = 0.f;
#pragma unroll
                for (int j = 0; j < 16; ++j)
                    y += ((const float*)wo4)[j] * snew[j];
                __hip_atomic_fetch_add(&out[(size_t)t * O_DIM + lane], y,
                                       __ATOMIC_RELAXED, __HIP_MEMORY_SCOPE_AGENT);
            }
        }
    }
}

// y_x[t,o] = Wout[o, :64] . x_t  -- plain writes, runs first
__global__ void esn_xpart(const float* __restrict__ X, const float* __restrict__ Wout,
                          float* __restrict__ out)
{
    const int idx = blockIdx.x * blockDim.x + threadIdx.x;  // t*64 + o
    const int t = idx >> 6, o = idx & 63;
    const float4* xr = (const float4*)(X + (size_t)t * I_DIM);
    const float4* wr = (const float4*)(Wout + (size_t)o * (I_DIM + R_DIM));
    float y = 0.f;
#pragma unroll
    for (int j = 0; j < 16; ++j) {
        float4 a = xr[j], b = wr[j];
        y += a.x * b.x + a.y * b.y + a.z * b.z + a.w * b.w;
    }
    out[idx] = y;
}

// HIST mode: out[t,o] += Wout[o, 64:] . Shist[t]  -- massively parallel, no atomics
__global__ void esn_readout(const float* __restrict__ Shist, const float* __restrict__ Wout,
                            float* __restrict__ out)
{
    const int idx = blockIdx.x * blockDim.x + threadIdx.x;  // t*64 + o
    const int t = idx >> 6, o = idx & 63;
    const float4* s4 = (const float4*)(Shist + (size_t)t * R_DIM);
    const float4* w4 = (const float4*)(Wout + (size_t)o * (I_DIM + R_DIM) + I_DIM);
    float y = 0.f;
#pragma unroll 4
    for (int j = 0; j < R_DIM / 4; ++j) {
        float4 a = s4[j], b = w4[j];
        y += a.x * b.x + a.y * b.y + a.z * b.z + a.w * b.w;
    }
    out[idx] += y;
}

extern "C" void kernel_launch(void* const* d_in, const int* in_sizes, int n_in,
                              void* d_out, int out_size, void* d_ws, size_t ws_size,
                              hipStream_t stream)
{
    (void)in_sizes; (void)n_in; (void)out_size;
    const float* X    = (const float*)d_in[0];
    const float* Win  = (const float*)d_in[1];
    const float* Wres = (const float*)d_in[2];
    const float* Wout = (const float*)d_in[3];
    float* out = (float*)d_out;

    unsigned* pairs = (unsigned*)d_ws;
    float* Shist = (float*)((char*)d_ws + 65536);
    const size_t hist_bytes = (size_t)T_DIM * R_DIM * sizeof(float);
    const int use_hist = (ws_size >= 65536 + hist_bytes) ? 1 : 0;

    // reset pair tags every call (stale tags would break polling)
    hipMemsetAsync(d_ws, 0, 2 * R_DIM * sizeof(unsigned), stream);

    // x-part of readout initializes all of d_out
    esn_xpart<<<(T_DIM * O_DIM) / 256, 256, 0, stream>>>(X, Wout, out);

    void* args[] = { (void*)&X, (void*)&Wres, (void*)&Win, (void*)&Wout,
                     (void*)&out, (void*)&pairs, (void*)&Shist, (void*)&use_hist };
    hipLaunchCooperativeKernel((const void*)esn_persist, dim3(NBLK), dim3(NTHR),
                               args, 0, stream);

    if (use_hist)
        esn_readout<<<(T_DIM * O_DIM) / 256, 256, 0, stream>>>(Shist, Wout, out);
}